// Round 1
// baseline (5396.693 us; speedup 1.0000x reference)
//
#include <hip/hip_runtime.h>
#include <cstdint>
#include <cstddef>

// Problem constants
#define B_   64
#define S_   512
#define ISZ  256
#define HSZ  512
#define KSZ  768     // I + H
#define NG   2048    // 4*H

typedef unsigned short u16;
typedef __attribute__((ext_vector_type(8))) short short8;
typedef __attribute__((ext_vector_type(4))) float floatx4;

// Workspace layout (bytes)
//  Wpack: 2 dirs * 2048 * 768 bf16 = 6,291,456
//  Xb   : 512*64*256 bf16        = 16,777,216
//  Ah   : 2*64*512 bf16          = 131,072   (h state, bf16, A-layout rows)
//  Cst  : 2*64*512 f32           = 262,144
static const size_t OFF_WPACK = 0;
static const size_t OFF_XB    = 6291456;
static const size_t OFF_AH    = OFF_XB + 16777216;
static const size_t OFF_CST   = OFF_AH + 131072;

__device__ __forceinline__ u16 f2bf(float f) {
    uint32_t u = __float_as_uint(f);
    return (u16)((u + 0x7fffu + ((u >> 16) & 1u)) >> 16);  // RNE
}

__device__ __forceinline__ float sigmoidf_(float x) {
    return 1.0f / (1.0f + __expf(-x));
}
__device__ __forceinline__ float tanhf_(float x) {
    // tanh(x) = 1 - 2/(exp(2x)+1); saturates correctly at +/-inf
    return 1.0f - 2.0f / (__expf(2.0f * x) + 1.0f);
}

// ---------------------------------------------------------------------------
// Pack W_f / W_b (768 x 2048 f32, row-major) into bf16 MFMA-B-fragment order,
// with column permutation p: gate-interleaved per 16-hidden-unit chunk.
//   p in [0,2048): c = p>>6 (chunk of 16 hid), gate = (p>>4)&3, hid = c*16 + (p&15)
//   original col = gate*512 + hid
// Element (dir, nb=p>>4, kb=k>>5, lane, j):
//   lane = ((k&31)>>3)*16 + (p&15), j = k&7
//   flat = ((dir*128 + nb)*24 + kb)*512 + lane*8 + j
// ---------------------------------------------------------------------------
__global__ __launch_bounds__(256) void pack_w(const float* __restrict__ Wf,
                                              const float* __restrict__ Wb,
                                              u16* __restrict__ wpack) {
    int tid = blockIdx.x * 256 + threadIdx.x;   // over 768*2048
    int dir = blockIdx.y;
    int p = tid & 2047;
    int k = tid >> 11;
    int gate = (p >> 4) & 3;
    int hid  = (p >> 6) * 16 + (p & 15);
    int col  = gate * HSZ + hid;
    const float* W = dir ? Wb : Wf;
    float v = W[(size_t)k * NG + col];
    int nb   = p >> 4;
    int lane = ((k & 31) >> 3) * 16 + (p & 15);
    size_t idx = (((size_t)(dir * 128 + nb) * 24 + (k >> 5)) * 512) + lane * 8 + (k & 7);
    wpack[idx] = f2bf(v);
}

// inputs (B,S,I) f32 -> Xb [t][b][i] bf16
__global__ __launch_bounds__(256) void pack_x(const float* __restrict__ x,
                                              u16* __restrict__ xb) {
    int tid = blockIdx.x * 256 + threadIdx.x;   // over S*B*I = 8,388,608
    int i = tid & 255;
    int b = (tid >> 8) & 63;
    int t = tid >> 14;
    xb[tid] = f2bf(x[((size_t)b * S_ + t) * ISZ + i]);
}

// ---------------------------------------------------------------------------
// One time step: both directions.
// grid = dim3(128, 2): blockIdx.y = dir; blockIdx.x: bg = &3 (batch group of 16),
//                      c = >>2 (chunk of 16 hidden units). block = 64 threads (1 wave).
// Wave computes gates for 16 batches x 16 hidden units x 4 gates via MFMA
// (M=16, N=64 permuted cols, K=768), then does the LSTM cell update in-register.
// ---------------------------------------------------------------------------
__global__ __launch_bounds__(64) void step_kernel(
    const u16* __restrict__ wpack, const u16* __restrict__ xb,
    u16* __restrict__ ah, float* __restrict__ cst,
    const float* __restrict__ bf_, const float* __restrict__ bb_,
    float* __restrict__ out, int t)
{
    const int l  = threadIdx.x;
    const int lm = l & 15;
    const int lq = l >> 4;
    const int bg = blockIdx.x & 3;
    const int c  = blockIdx.x >> 2;
    const int dir = blockIdx.y;

    const int tx = dir ? (S_ - 1 - t) : t;   // which input timestep this dir reads

    // A-fragment pointers: batch row = bg*16 + lm, k-offset lane-part = lq*8
    const u16* aptr_x = xb + (((size_t)tx * B_ + bg * 16 + lm) * ISZ) + lq * 8;
    const u16* aptr_h = ah + (((size_t)dir * B_ + bg * 16 + lm) * HSZ) + lq * 8;
    // B-fragment pointer: nb base = c*4 (+gate), per (gate,kb): +(gate*24+kb)*512
    const u16* wptr = wpack + ((size_t)(dir * 128 + c * 4) * 24) * 512 + l * 8;

    floatx4 acc[4];
#pragma unroll
    for (int g = 0; g < 4; ++g) acc[g] = (floatx4){0.f, 0.f, 0.f, 0.f};

#pragma unroll 4
    for (int kb = 0; kb < 24; ++kb) {
        short8 a;
        if (kb < 8) a = *(const short8*)(aptr_x + kb * 32);
        else        a = *(const short8*)(aptr_h + (kb - 8) * 32);
        short8 w0 = *(const short8*)(wptr + (0 * 24 + kb) * 512);
        short8 w1 = *(const short8*)(wptr + (1 * 24 + kb) * 512);
        short8 w2 = *(const short8*)(wptr + (2 * 24 + kb) * 512);
        short8 w3 = *(const short8*)(wptr + (3 * 24 + kb) * 512);
        acc[0] = __builtin_amdgcn_mfma_f32_16x16x32_bf16(a, w0, acc[0], 0, 0, 0);
        acc[1] = __builtin_amdgcn_mfma_f32_16x16x32_bf16(a, w1, acc[1], 0, 0, 0);
        acc[2] = __builtin_amdgcn_mfma_f32_16x16x32_bf16(a, w2, acc[2], 0, 0, 0);
        acc[3] = __builtin_amdgcn_mfma_f32_16x16x32_bf16(a, w3, acc[3], 0, 0, 0);
    }

    // Epilogue: lane l holds, for rows m = lq*4 + r (r=0..3), the 4 gate values
    // of hidden unit hid = c*16 + lm  (acc[g][r], g = f,i,o,g).
    const int hid = c * 16 + lm;
    const float* bias = dir ? bb_ : bf_;
    const float Bf = bias[hid];
    const float Bi = bias[HSZ + hid];
    const float Bo = bias[2 * HSZ + hid];
    const float Bg = bias[3 * HSZ + hid];

    const int t_out = dir ? (S_ - 1 - t) : t;
    const bool first = (t < 256);   // holds for both dirs (see derivation)

#pragma unroll
    for (int r = 0; r < 4; ++r) {
        const int b = bg * 16 + lq * 4 + r;
        float fg = acc[0][r] + Bf;
        float ig = acc[1][r] + Bi;
        float og = acc[2][r] + Bo;
        float gg = acc[3][r] + Bg;
        const size_t cidx = ((size_t)dir * B_ + b) * HSZ + hid;
        float cold = cst[cidx];
        float cn = sigmoidf_(fg) * cold + sigmoidf_(ig) * tanhf_(gg);
        float hn = sigmoidf_(og) * tanhf_(cn);
        cst[cidx] = cn;
        ah[cidx] = f2bf(hn);
        const size_t oidx = ((size_t)b * S_ + t_out) * HSZ + hid;
        const float val = 0.5f * hn;
        if (first) out[oidx] = val;
        else       out[oidx] += val;
    }
}

extern "C" void kernel_launch(void* const* d_in, const int* in_sizes, int n_in,
                              void* d_out, int out_size, void* d_ws, size_t ws_size,
                              hipStream_t stream) {
    const float* x  = (const float*)d_in[0];
    const float* Wf = (const float*)d_in[1];
    const float* bf = (const float*)d_in[2];
    const float* Wb = (const float*)d_in[3];
    const float* bb = (const float*)d_in[4];
    float* out = (float*)d_out;
    char* ws = (char*)d_ws;

    u16*   wpack = (u16*)(ws + OFF_WPACK);
    u16*   xb    = (u16*)(ws + OFF_XB);
    u16*   ah    = (u16*)(ws + OFF_AH);
    float* cst   = (float*)(ws + OFF_CST);

    // zero h and c state (ws is poisoned 0xAA before every call)
    hipMemsetAsync(ws + OFF_AH, 0, 131072 + 262144, stream);

    pack_w<<<dim3(6144, 2), 256, 0, stream>>>(Wf, Wb, wpack);
    pack_x<<<dim3(32768), 256, 0, stream>>>(x, xb);

    for (int t = 0; t < S_; ++t) {
        step_kernel<<<dim3(128, 2), 64, 0, stream>>>(wpack, xb, ah, cst, bf, bb, out, t);
    }
}

// Round 3
// 4040.358 us; speedup vs baseline: 1.3357x; 1.3357x over previous
//
#include <hip/hip_runtime.h>
#include <cstdint>
#include <cstddef>

// Problem constants
#define B_   64
#define S_   512
#define ISZ  256
#define HSZ  512
#define NG   2048    // 4*H

typedef unsigned short u16;
typedef __attribute__((ext_vector_type(8))) short short8;
typedef __attribute__((ext_vector_type(4))) float floatx4;

// Workspace layout (bytes)
static const size_t OFF_WPACK = 0;                       // 2*2048*768*2      = 6,291,456
static const size_t OFF_XB    = 6291456;                 // 512*64*256*2      = 16,777,216
static const size_t OFF_HG    = OFF_XB + 16777216;       // 2*64*512*2        = 131,072
static const size_t OFF_FLAGS = OFF_HG + 131072;         // 8*512*4           = 16,384

__device__ __forceinline__ u16 f2bf(float f) {
    uint32_t u = __float_as_uint(f);
    return (u16)((u + 0x7fffu + ((u >> 16) & 1u)) >> 16);  // RNE
}
__device__ __forceinline__ float sigmoidf_(float x) {
    return 1.0f / (1.0f + __expf(-x));
}
__device__ __forceinline__ float tanhf_(float x) {
    return 1.0f - 2.0f / (__expf(2.0f * x) + 1.0f);
}

// ---------------------------------------------------------------------------
// Pack W_f / W_b (768 x 2048 f32, row-major) into bf16 MFMA-B-fragment order,
// gate-interleaved per 16-hidden-unit chunk (same layout as round 1):
//   flat = ((dir*128 + nb)*24 + kb)*512 + lane*8 + j
//   nb = 16-col tile; for chunk c, gate g: nb = 4c+g; col = g*512 + c*16 + (p&15)
// ---------------------------------------------------------------------------
__global__ __launch_bounds__(256) void pack_w(const float* __restrict__ Wf,
                                              const float* __restrict__ Wb,
                                              u16* __restrict__ wpack) {
    int tid = blockIdx.x * 256 + threadIdx.x;   // over 768*2048
    int dir = blockIdx.y;
    int p = tid & 2047;
    int k = tid >> 11;
    int gate = (p >> 4) & 3;
    int hid  = (p >> 6) * 16 + (p & 15);
    int col  = gate * HSZ + hid;
    const float* W = dir ? Wb : Wf;
    float v = W[(size_t)k * NG + col];
    int nb   = p >> 4;
    int lane = ((k & 31) >> 3) * 16 + (p & 15);
    size_t idx = (((size_t)(dir * 128 + nb) * 24 + (k >> 5)) * 512) + lane * 8 + (k & 7);
    wpack[idx] = f2bf(v);
}

// inputs (B,S,I) f32 -> Xb [t][b][i] bf16
__global__ __launch_bounds__(256) void pack_x(const float* __restrict__ x,
                                              u16* __restrict__ xb) {
    int tid = blockIdx.x * 256 + threadIdx.x;   // over S*B*I = 8,388,608
    int i = tid & 255;
    int b = (tid >> 8) & 63;
    int t = tid >> 14;
    xb[tid] = f2bf(x[((size_t)b * S_ + t) * ISZ + i]);
}

// ---------------------------------------------------------------------------
// Persistent BiLSTM kernel.
// grid = 256 blocks x 128 threads (2 waves).
//   chain = blockIdx.x & 7  : dir = chain>>2, bg = chain&3 (batches bg*16..+15)
//   c     = blockIdx.x >> 3 : hidden-unit chunk (16 units), 0..31
//   wave gp = tid>>6        : gate pair (f,i) or (o,g)
// Each wave holds its W slice (2 N-tiles x K=768 = 192 VGPRs) in registers for
// the whole sequence. Per step: load A frags (x ++ h), 48 MFMAs, gate exchange
// through LDS, cell update (c-state in thread registers), write h (bf16) for
// the chain, atomicAdd 0.5*h into out, then a 32-block chain barrier.
// ---------------------------------------------------------------------------
__global__ __launch_bounds__(128, 1) void bilstm_persistent(
    const u16* __restrict__ wpack, const u16* __restrict__ xb,
    u16* __restrict__ hglob, int* __restrict__ flags,
    const float* __restrict__ bf_, const float* __restrict__ bb_,
    float* __restrict__ out)
{
    const int tid = threadIdx.x;
    const int l   = tid & 63;
    const int lm  = l & 15;
    const int lq  = l >> 4;
    const int gp  = tid >> 6;            // 0: gates f,i ; 1: gates o,g
    const int chain = blockIdx.x & 7;
    const int c     = blockIdx.x >> 3;
    const int dir   = chain >> 2;
    const int bg    = chain & 3;

    __shared__ float gsm[4][16][20];     // [gate][hid_l][batch_l(+pad)]

    // ---- load W fragments into registers (once) ----
    const u16* wbase = wpack + ((size_t)(dir * 128 + c * 4 + gp * 2) * 24) * 512 + l * 8;
    short8 wfrag[48];                    // [kb*2 + n], n in {0,1}
#pragma unroll
    for (int kb = 0; kb < 24; ++kb) {
#pragma unroll
        for (int n = 0; n < 2; ++n)
            wfrag[kb * 2 + n] = *(const short8*)(wbase + ((size_t)(n * 24 + kb)) * 512);
    }

    // ---- per-thread cell assignment (epilogue phase) ----
    const int hid_l = tid >> 3;          // 0..15
    const int bl0   = (tid & 7) * 2;     // batches bl0, bl0+1
    const int hid   = c * 16 + hid_l;
    const float* bias = dir ? bb_ : bf_;
    const float Bf = bias[hid];
    const float Bi = bias[HSZ + hid];
    const float Bo = bias[2 * HSZ + hid];
    const float Bg = bias[3 * HSZ + hid];
    float cprev0 = 0.0f, cprev1 = 0.0f;

    // A-fragment base pointers (row = batch, lane k-offset = lq*8)
    const u16* abx = xb + ((size_t)(bg * 16 + lm)) * ISZ + lq * 8;     // + tx*64*ISZ
    const u16* abh = hglob + ((size_t)(dir * 64 + bg * 16 + lm)) * HSZ + lq * 8;
    int* flagp = flags + chain * S_;

    for (int t = 0; t < S_; ++t) {
        const int tx = dir ? (S_ - 1 - t) : t;

        // ---- load all 24 A fragments (x: kb 0..7, h: kb 8..23) ----
        short8 afrag[24];
        const u16* ax = abx + (size_t)tx * (64 * ISZ);
#pragma unroll
        for (int kb = 0; kb < 8; ++kb)
            afrag[kb] = *(const short8*)(ax + kb * 32);
#pragma unroll
        for (int kb = 0; kb < 16; ++kb)
            afrag[8 + kb] = *(const short8*)(abh + kb * 32);

        // ---- 48 MFMAs ----
        floatx4 acc0 = (floatx4){0.f, 0.f, 0.f, 0.f};
        floatx4 acc1 = (floatx4){0.f, 0.f, 0.f, 0.f};
#pragma unroll
        for (int kb = 0; kb < 24; ++kb) {
            acc0 = __builtin_amdgcn_mfma_f32_16x16x32_bf16(afrag[kb], wfrag[kb * 2 + 0], acc0, 0, 0, 0);
            acc1 = __builtin_amdgcn_mfma_f32_16x16x32_bf16(afrag[kb], wfrag[kb * 2 + 1], acc1, 0, 0, 0);
        }

        // ---- gate exchange via LDS ----
        // acc_n: gate g = gp*2+n; C layout: col(=hid_l)=lm, row(=batch_l)=lq*4+r
#pragma unroll
        for (int r = 0; r < 4; ++r) {
            gsm[gp * 2 + 0][lm][lq * 4 + r] = acc0[r];
            gsm[gp * 2 + 1][lm][lq * 4 + r] = acc1[r];
        }
        __syncthreads();

        // ---- cell update: 2 cells per thread, c-state in registers ----
        {
            float f0 = gsm[0][hid_l][bl0]     + Bf;
            float i0 = gsm[1][hid_l][bl0]     + Bi;
            float o0 = gsm[2][hid_l][bl0]     + Bo;
            float g0 = gsm[3][hid_l][bl0]     + Bg;
            float f1 = gsm[0][hid_l][bl0 + 1] + Bf;
            float i1 = gsm[1][hid_l][bl0 + 1] + Bi;
            float o1 = gsm[2][hid_l][bl0 + 1] + Bo;
            float g1 = gsm[3][hid_l][bl0 + 1] + Bg;
            float cn0 = sigmoidf_(f0) * cprev0 + sigmoidf_(i0) * tanhf_(g0);
            float cn1 = sigmoidf_(f1) * cprev1 + sigmoidf_(i1) * tanhf_(g1);
            float h0 = sigmoidf_(o0) * tanhf_(cn0);
            float h1 = sigmoidf_(o1) * tanhf_(cn1);
            cprev0 = cn0; cprev1 = cn1;

            const int b0 = bg * 16 + bl0;
            hglob[((size_t)(dir * 64 + b0)) * HSZ + hid]     = f2bf(h0);
            hglob[((size_t)(dir * 64 + b0 + 1)) * HSZ + hid] = f2bf(h1);
            atomicAdd(&out[((size_t)b0 * S_ + tx) * HSZ + hid],       0.5f * h0);
            atomicAdd(&out[((size_t)(b0 + 1) * S_ + tx) * HSZ + hid], 0.5f * h1);
        }
        __syncthreads();   // LDS reuse + all h writes issued before signal

        // ---- chain barrier (32 blocks), step-indexed flag ----
        if (tid == 0) {
            __builtin_amdgcn_fence(__ATOMIC_RELEASE, "agent");
            __hip_atomic_fetch_add(&flagp[t], 1, __ATOMIC_RELAXED, __HIP_MEMORY_SCOPE_AGENT);
            while (__hip_atomic_load(&flagp[t], __ATOMIC_RELAXED, __HIP_MEMORY_SCOPE_AGENT) < 32) {
                __builtin_amdgcn_s_sleep(2);
            }
            __builtin_amdgcn_fence(__ATOMIC_ACQUIRE, "agent");
        }
        __syncthreads();
    }
}

extern "C" void kernel_launch(void* const* d_in, const int* in_sizes, int n_in,
                              void* d_out, int out_size, void* d_ws, size_t ws_size,
                              hipStream_t stream) {
    const float* x  = (const float*)d_in[0];
    const float* Wf = (const float*)d_in[1];
    const float* bf = (const float*)d_in[2];
    const float* Wb = (const float*)d_in[3];
    const float* bb = (const float*)d_in[4];
    float* out = (float*)d_out;
    char* ws = (char*)d_ws;

    u16*   wpack = (u16*)(ws + OFF_WPACK);
    u16*   xb    = (u16*)(ws + OFF_XB);
    u16*   hglob = (u16*)(ws + OFF_HG);
    int*   flags = (int*)(ws + OFF_FLAGS);

    // zero h state + flags (ws poisoned 0xAA), and the output (we accumulate)
    (void)hipMemsetAsync(ws + OFF_HG, 0, 131072 + 16384, stream);
    (void)hipMemsetAsync(d_out, 0, (size_t)out_size * sizeof(float), stream);

    pack_w<<<dim3(6144, 2), 256, 0, stream>>>(Wf, Wb, wpack);
    pack_x<<<dim3(32768), 256, 0, stream>>>(x, xb);

    bilstm_persistent<<<dim3(256), dim3(128), 0, stream>>>(
        wpack, xb, hglob, flags, bf, bb, out);
}